// Round 4
// baseline (540.634 us; speedup 1.0000x reference)
//
#include <hip/hip_runtime.h>

#define NODES 50000
#define CH 128

using frag_ab = __attribute__((ext_vector_type(8))) short;   // 8 bf16
using frag_cd = __attribute__((ext_vector_type(4))) float;   // 4 fp32

__device__ __forceinline__ float bf2f(ushort u) {
    union { unsigned u; float f; } v; v.u = ((unsigned)u) << 16; return v.f;
}
__device__ __forceinline__ ushort f2bf(float f) {
    union { float f; unsigned u; } v; v.f = f;
    unsigned r = v.u + 0x7fff + ((v.u >> 16) & 1);   // RNE
    return (ushort)(r >> 16);
}

// ---------------- prep: all 5 weight transposes in ONE kernel ----------------
// W [K,128] fp32 -> Wt [128,K] bf16. Blocks 0..191: W_lin (K=384, 2 k-rows/blk).
// Blocks 192..447: four 128x128 mats, 64 blocks each.
__global__ void prep_weights(const float* __restrict__ Wlin,
                             const float* __restrict__ W1l, const float* __restrict__ W1r,
                             const float* __restrict__ W2l, const float* __restrict__ W2r,
                             ushort* __restrict__ o0, ushort* __restrict__ o1,
                             ushort* __restrict__ o2, ushort* __restrict__ o3,
                             ushort* __restrict__ o4) {
    int b = blockIdx.x;
    const float* W; ushort* O; int K; int kb;
    if (b < 192) { W = Wlin; O = o0; K = 384; kb = b; }
    else {
        int j = (b - 192) >> 6; kb = (b - 192) & 63; K = 128;
        W = (j == 0) ? W1l : (j == 1) ? W1r : (j == 2) ? W2l : W2r;
        O = (j == 0) ? o1  : (j == 1) ? o2  : (j == 2) ? o3  : o4;
    }
    int k = kb * 2 + threadIdx.y;
    int n = threadIdx.x;
    if (k < K) O[(size_t)n * K + k] = f2bf(W[(size_t)k * 128 + n]);
}

// ---------------- CSR build ----------------

__global__ void zero_ints(int* p, int n) {
    int i = blockIdx.x * blockDim.x + threadIdx.x;
    if (i < n) p[i] = 0;
}

__global__ void count_deg(const int* __restrict__ ei, int E, int* __restrict__ deg) {
    int e = blockIdx.x * blockDim.x + threadIdx.x;
    if (e < E) atomicAdd(&deg[ei[E + e]], 1);
}

__global__ __launch_bounds__(256) void scan_p1(const int* __restrict__ deg,
                                               int* __restrict__ bsums, int N) {
    __shared__ int s[256];
    int t = threadIdx.x;
    int i = blockIdx.x * 256 + t;
    s[t] = (i < N) ? deg[i] : 0;
    __syncthreads();
    for (int off = 128; off > 0; off >>= 1) {
        if (t < off) s[t] += s[t + off];
        __syncthreads();
    }
    if (t == 0) bsums[blockIdx.x] = s[0];
}

__global__ __launch_bounds__(256) void scan_p2(int* __restrict__ bsums, int nb) {
    __shared__ int s[256];
    int t = threadIdx.x;
    int v = (t < nb) ? bsums[t] : 0;
    s[t] = v;
    __syncthreads();
    for (int off = 1; off < 256; off <<= 1) {
        int u = (t >= off) ? s[t - off] : 0;
        __syncthreads();
        s[t] += u;
        __syncthreads();
    }
    if (t < nb) bsums[t] = s[t] - v;
}

__global__ __launch_bounds__(256) void scan_p3(const int* __restrict__ deg,
                                               const int* __restrict__ boffs,
                                               int* __restrict__ offsets, int N) {
    __shared__ int s[256];
    int t = threadIdx.x;
    int i = blockIdx.x * 256 + t;
    int v = (i < N) ? deg[i] : 0;
    s[t] = v;
    __syncthreads();
    for (int off = 1; off < 256; off <<= 1) {
        int u = (t >= off) ? s[t - off] : 0;
        __syncthreads();
        s[t] += u;
        __syncthreads();
    }
    int excl = boffs[blockIdx.x] + s[t] - v;
    if (i < N) offsets[i] = excl;
    if (i == N - 1) offsets[N] = excl + v;
}

__global__ void fill_csr(const int* __restrict__ ei, int E,
                         const int* __restrict__ offsets,
                         int* __restrict__ cursor, int* __restrict__ csr) {
    int e = blockIdx.x * blockDim.x + threadIdx.x;
    if (e < E) {
        int d = ei[E + e];
        int pos = atomicAdd(&cursor[d], 1);
        csr[offsets[d] + pos] = ei[e];
    }
}

// ---------------- gemm_lin: out[N,128](bf16) = f2bf(x) @ WtLin^T + bias ----------------
// x fp32 [N,384], converted inline during A-tile staging.
__global__ __launch_bounds__(256) void gemm_lin(
    const float* __restrict__ A, const ushort* __restrict__ Wt,
    const float* __restrict__ bias, ushort* __restrict__ out, int N)
{
    __shared__ ushort As[128 * 32];
    __shared__ ushort Bs[128 * 32];
    const int tid = threadIdx.x;
    const int lane = tid & 63;
    const int wave = tid >> 6;
    const int wr = wave >> 1, wc = wave & 1;
    const int row0 = blockIdx.x * 128;
    const int l15 = lane & 15, quad = lane >> 4;

    frag_cd acc[4][4];
#pragma unroll
    for (int i = 0; i < 4; ++i)
#pragma unroll
        for (int j = 0; j < 4; ++j) acc[i][j] = (frag_cd){0.f, 0.f, 0.f, 0.f};

#pragma unroll 1
    for (int k0 = 0; k0 < 384; k0 += 32) {
        __syncthreads();
        // A tile: 128 rows x 32 k fp32 -> bf16; 1024 float4, 4/thread
#pragma unroll
        for (int i = 0; i < 4; ++i) {
            int e = i * 256 + tid;
            int r = e >> 3, q = e & 7;
            int gr = row0 + r; if (gr > N - 1) gr = N - 1;
            float4 v = *(const float4*)(A + (size_t)gr * 384 + k0 + q * 4);
            ushort4 o; o.x = f2bf(v.x); o.y = f2bf(v.y); o.z = f2bf(v.z); o.w = f2bf(v.w);
            *(ushort4*)(As + r * 32 + q * 4) = o;
        }
#pragma unroll
        for (int i = 0; i < 2; ++i) {
            int e = i * 256 + tid;
            int nn = e >> 2, kq = e & 3;
            uint4 v = *(const uint4*)(Wt + (size_t)nn * 384 + k0 + kq * 8);
            *(uint4*)(Bs + e * 8) = v;
        }
        __syncthreads();

        frag_ab a[4], b[4];
#pragma unroll
        for (int i = 0; i < 4; ++i)
            a[i] = *(const frag_ab*)(As + (wr * 64 + i * 16 + l15) * 32 + quad * 8);
#pragma unroll
        for (int j = 0; j < 4; ++j)
            b[j] = *(const frag_ab*)(Bs + (wc * 64 + j * 16 + l15) * 32 + quad * 8);
#pragma unroll
        for (int i = 0; i < 4; ++i)
#pragma unroll
            for (int j = 0; j < 4; ++j)
                acc[i][j] = __builtin_amdgcn_mfma_f32_16x16x32_bf16(a[i], b[j], acc[i][j], 0, 0, 0);
    }

#pragma unroll
    for (int i = 0; i < 4; ++i)
#pragma unroll
        for (int r = 0; r < 4; ++r) {
            int row = row0 + wr * 64 + i * 16 + quad * 4 + r;
            if (row < N)
#pragma unroll
                for (int j = 0; j < 4; ++j) {
                    int col = wc * 64 + j * 16 + l15;
                    out[(size_t)row * 128 + col] = f2bf(acc[i][j][r] + bias[col]);
                }
        }
}

// ---------------- sage_fused: out = act( mean_agg(h)@Wl + h@Wr + bias ) ----------------
// 128-row tile/block. A-tile staged chunk-major As[4][128][32] (m97-proven frag layout).
// Part 1: As <- gathered neighbor means (computed in-kernel), Bs <- Wtl.
// Part 2: As <- h rows direct,                         Bs <- Wtr.
template <bool RELU>
__global__ __launch_bounds__(256) void sage_fused(
    const ushort* __restrict__ h, const int* __restrict__ csr,
    const int* __restrict__ offsets,
    const ushort* __restrict__ Wtl, const ushort* __restrict__ Wtr,
    const float* __restrict__ bias, ushort* __restrict__ out, int N)
{
    __shared__ ushort As[4][128][32];
    __shared__ ushort Bs[4][128][32];
    const int tid = threadIdx.x;
    const int lane = tid & 63;
    const int wave = tid >> 6;
    const int wr = wave >> 1, wc = wave & 1;
    const int row0 = blockIdx.x * 128;
    const int l15 = lane & 15, quad = lane >> 4;
    const int mychunk = lane >> 4;          // which 32-ch chunk this lane's 2 channels land in
    const int myoff = (lane & 15) * 2;

    frag_cd acc[4][4];
#pragma unroll
    for (int i = 0; i < 4; ++i)
#pragma unroll
        for (int j = 0; j < 4; ++j) acc[i][j] = (frag_cd){0.f, 0.f, 0.f, 0.f};

    // ---- part 1 staging: Bs <- Wtl (chunk-major), As <- gather-mean ----
#pragma unroll
    for (int i = 0; i < 8; ++i) {
        int e = i * 256 + tid;
        int n = e >> 4, s = e & 15;
        uint4 v = *(const uint4*)(Wtl + (size_t)n * 128 + s * 8);
        *(uint4*)(&Bs[s >> 2][n][(s & 3) * 8]) = v;
    }
#pragma unroll 1
    for (int rr = 0; rr < 32; ++rr) {
        int r = wave * 32 + rr;
        int node = row0 + r; if (node > N - 1) node = N - 1;
        int s0 = offsets[node], e0 = offsets[node + 1];
        float a0 = 0.f, a1 = 0.f;
        int n = s0;
        for (; n + 3 < e0; n += 4) {
            int i0 = csr[n], i1 = csr[n + 1], i2 = csr[n + 2], i3 = csr[n + 3];
            uint v0 = *(const uint*)(h + (size_t)i0 * CH + lane * 2);
            uint v1 = *(const uint*)(h + (size_t)i1 * CH + lane * 2);
            uint v2 = *(const uint*)(h + (size_t)i2 * CH + lane * 2);
            uint v3 = *(const uint*)(h + (size_t)i3 * CH + lane * 2);
            a0 += bf2f((ushort)(v0 & 0xffff)) + bf2f((ushort)(v1 & 0xffff))
                + bf2f((ushort)(v2 & 0xffff)) + bf2f((ushort)(v3 & 0xffff));
            a1 += bf2f((ushort)(v0 >> 16)) + bf2f((ushort)(v1 >> 16))
                + bf2f((ushort)(v2 >> 16)) + bf2f((ushort)(v3 >> 16));
        }
        for (; n < e0; ++n) {
            uint v0 = *(const uint*)(h + (size_t)csr[n] * CH + lane * 2);
            a0 += bf2f((ushort)(v0 & 0xffff));
            a1 += bf2f((ushort)(v0 >> 16));
        }
        float d = fmaxf((float)(e0 - s0), 1.f);
        uint o = ((uint)f2bf(a1 / d) << 16) | (uint)f2bf(a0 / d);
        *(uint*)(&As[mychunk][r][myoff]) = o;
    }
    __syncthreads();
#pragma unroll
    for (int c = 0; c < 4; ++c) {
        frag_ab a[4], b[4];
#pragma unroll
        for (int i = 0; i < 4; ++i)
            a[i] = *(const frag_ab*)(&As[c][wr * 64 + i * 16 + l15][quad * 8]);
#pragma unroll
        for (int j = 0; j < 4; ++j)
            b[j] = *(const frag_ab*)(&Bs[c][wc * 64 + j * 16 + l15][quad * 8]);
#pragma unroll
        for (int i = 0; i < 4; ++i)
#pragma unroll
            for (int j = 0; j < 4; ++j)
                acc[i][j] = __builtin_amdgcn_mfma_f32_16x16x32_bf16(a[i], b[j], acc[i][j], 0, 0, 0);
    }
    __syncthreads();

    // ---- part 2 staging: Bs <- Wtr, As <- h rows direct ----
#pragma unroll
    for (int i = 0; i < 8; ++i) {
        int e = i * 256 + tid;
        int n = e >> 4, s = e & 15;
        uint4 v = *(const uint4*)(Wtr + (size_t)n * 128 + s * 8);
        *(uint4*)(&Bs[s >> 2][n][(s & 3) * 8]) = v;
    }
#pragma unroll
    for (int i = 0; i < 8; ++i) {
        int e = i * 256 + tid;
        int r = e >> 4, s = e & 15;
        int gr = row0 + r; if (gr > N - 1) gr = N - 1;
        uint4 v = *(const uint4*)(h + (size_t)gr * CH + s * 8);
        *(uint4*)(&As[s >> 2][r][(s & 3) * 8]) = v;
    }
    __syncthreads();
#pragma unroll
    for (int c = 0; c < 4; ++c) {
        frag_ab a[4], b[4];
#pragma unroll
        for (int i = 0; i < 4; ++i)
            a[i] = *(const frag_ab*)(&As[c][wr * 64 + i * 16 + l15][quad * 8]);
#pragma unroll
        for (int j = 0; j < 4; ++j)
            b[j] = *(const frag_ab*)(&Bs[c][wc * 64 + j * 16 + l15][quad * 8]);
#pragma unroll
        for (int i = 0; i < 4; ++i)
#pragma unroll
            for (int j = 0; j < 4; ++j)
                acc[i][j] = __builtin_amdgcn_mfma_f32_16x16x32_bf16(a[i], b[j], acc[i][j], 0, 0, 0);
    }

    // epilogue: C/D layout col=lane&15, row=quad*4+reg (m89-verified)
#pragma unroll
    for (int i = 0; i < 4; ++i)
#pragma unroll
        for (int r = 0; r < 4; ++r) {
            int row = row0 + wr * 64 + i * 16 + quad * 4 + r;
            if (row < N)
#pragma unroll
                for (int j = 0; j < 4; ++j) {
                    int col = wc * 64 + j * 16 + l15;
                    float v = acc[i][j][r] + bias[col];
                    if (RELU) v = fmaxf(v, 0.f);
                    out[(size_t)row * 128 + col] = f2bf(v);
                }
        }
}

// ---------------- classifier: 2 edges per 16-lane group (4 outstanding gathers) ----
__device__ __forceinline__ float dot8(uint4 va, uint4 vb) {
    float p = 0.f;
    p += bf2f((ushort)(va.x & 0xffff)) * bf2f((ushort)(vb.x & 0xffff));
    p += bf2f((ushort)(va.x >> 16))    * bf2f((ushort)(vb.x >> 16));
    p += bf2f((ushort)(va.y & 0xffff)) * bf2f((ushort)(vb.y & 0xffff));
    p += bf2f((ushort)(va.y >> 16))    * bf2f((ushort)(vb.y >> 16));
    p += bf2f((ushort)(va.z & 0xffff)) * bf2f((ushort)(vb.z & 0xffff));
    p += bf2f((ushort)(va.z >> 16))    * bf2f((ushort)(vb.z >> 16));
    p += bf2f((ushort)(va.w & 0xffff)) * bf2f((ushort)(vb.w & 0xffff));
    p += bf2f((ushort)(va.w >> 16))    * bf2f((ushort)(vb.w >> 16));
    return p;
}

__global__ void classify_bf(const ushort* __restrict__ h2, const int* __restrict__ eli,
                            int EL, float* __restrict__ out) {
    int gt = blockIdx.x * blockDim.x + threadIdx.x;
    int g0 = (gt >> 4) * 2;
    int lane = gt & 15;
    if (g0 >= EL) return;
    int g1 = g0 + 1; if (g1 >= EL) g1 = g0;
    int a0 = eli[g0], b0 = eli[EL + g0];
    int a1 = eli[g1], b1 = eli[EL + g1];
    uint4 va0 = *((const uint4*)(h2 + (size_t)a0 * CH) + lane);
    uint4 vb0 = *((const uint4*)(h2 + (size_t)b0 * CH) + lane);
    uint4 va1 = *((const uint4*)(h2 + (size_t)a1 * CH) + lane);
    uint4 vb1 = *((const uint4*)(h2 + (size_t)b1 * CH) + lane);
    float p0 = dot8(va0, vb0);
    float p1 = dot8(va1, vb1);
    p0 += __shfl_down(p0, 8, 16); p1 += __shfl_down(p1, 8, 16);
    p0 += __shfl_down(p0, 4, 16); p1 += __shfl_down(p1, 4, 16);
    p0 += __shfl_down(p0, 2, 16); p1 += __shfl_down(p1, 2, 16);
    p0 += __shfl_down(p0, 1, 16); p1 += __shfl_down(p1, 1, 16);
    if (lane == 0) {
        out[g0] = p0;
        if (g1 != g0) out[g1] = p1;
    }
}

extern "C" void kernel_launch(void* const* d_in, const int* in_sizes, int n_in,
                              void* d_out, int out_size, void* d_ws, size_t ws_size,
                              hipStream_t stream) {
    const float* x     = (const float*)d_in[0];
    const int*   ei    = (const int*)d_in[1];
    const int*   eli   = (const int*)d_in[2];
    const float* W_lin = (const float*)d_in[3];
    const float* b_lin = (const float*)d_in[4];
    const float* W1l   = (const float*)d_in[5];
    const float* b1    = (const float*)d_in[6];
    const float* W1r   = (const float*)d_in[7];
    const float* W2l   = (const float*)d_in[8];
    const float* b2    = (const float*)d_in[9];
    const float* W2r   = (const float*)d_in[10];
    float* out = (float*)d_out;

    const int E  = in_sizes[1] / 2;
    const int EL = in_sizes[2] / 2;
    const int N  = NODES;

    char* ws = (char*)d_ws;
    size_t off = 0;
    auto alloc = [&](size_t bytes) -> void* {
        void* p = ws + off;
        off += (bytes + 255) & ~(size_t)255;
        return p;
    };
    ushort* n0    = (ushort*)alloc((size_t)N * CH * sizeof(ushort));  // h0
    ushort* n1    = (ushort*)alloc((size_t)N * CH * sizeof(ushort));  // h2
    ushort* n2    = (ushort*)alloc((size_t)N * CH * sizeof(ushort));  // h1
    ushort* WtLin = (ushort*)alloc((size_t)CH * 384 * sizeof(ushort));
    ushort* Wt1l  = (ushort*)alloc((size_t)CH * CH * sizeof(ushort));
    ushort* Wt1r  = (ushort*)alloc((size_t)CH * CH * sizeof(ushort));
    ushort* Wt2l  = (ushort*)alloc((size_t)CH * CH * sizeof(ushort));
    ushort* Wt2r  = (ushort*)alloc((size_t)CH * CH * sizeof(ushort));
    int* deg     = (int*)alloc((size_t)2 * N * sizeof(int));
    int* cursor  = deg + N;
    int* offsets = (int*)alloc((size_t)(N + 16) * sizeof(int));
    int* csr     = (int*)alloc((size_t)E * sizeof(int));
    int* bsums   = (int*)alloc((size_t)256 * sizeof(int));
    (void)ws_size; (void)n_in; (void)out_size;

    // ---- prep: all weight transposes in one dispatch ----
    prep_weights<<<dim3(448), dim3(128, 2), 0, stream>>>(
        W_lin, W1l, W1r, W2l, W2r, WtLin, Wt1l, Wt1r, Wt2l, Wt2r);

    // ---- CSR build ----
    const int nb = (N + 255) / 256;
    zero_ints<<<dim3((2 * N + 255) / 256), dim3(256), 0, stream>>>(deg, 2 * N);
    count_deg<<<dim3((E + 255) / 256), dim3(256), 0, stream>>>(ei, E, deg);
    scan_p1<<<dim3(nb), dim3(256), 0, stream>>>(deg, bsums, N);
    scan_p2<<<dim3(1), dim3(256), 0, stream>>>(bsums, nb);
    scan_p3<<<dim3(nb), dim3(256), 0, stream>>>(deg, bsums, offsets, N);
    fill_csr<<<dim3((E + 255) / 256), dim3(256), 0, stream>>>(ei, E, offsets, cursor, csr);

    const int gblocks = (N + 127) / 128;

    // h0 = bf16(x) @ W_lin + b_lin   (fp32->bf16 fused into staging)
    gemm_lin<<<dim3(gblocks), dim3(256), 0, stream>>>(x, WtLin, b_lin, n0, N);

    // layer 1: h1 = relu(mean(h0)@W1l + h0@W1r + b1)
    sage_fused<true><<<dim3(gblocks), dim3(256), 0, stream>>>(
        n0, csr, offsets, Wt1l, Wt1r, b1, n2, N);

    // layer 2: h2 = mean(h1)@W2l + h1@W2r + b2
    sage_fused<false><<<dim3(gblocks), dim3(256), 0, stream>>>(
        n2, csr, offsets, Wt2l, Wt2r, b2, n1, N);

    // classifier
    long long groups = ((long long)EL + 1) / 2;
    long long cls_threads = groups * 16;
    classify_bf<<<dim3((int)((cls_threads + 255) / 256)), dim3(256), 0, stream>>>(
        n1, eli, EL, out);
}

// Round 5
// 330.222 us; speedup vs baseline: 1.6372x; 1.6372x over previous
//
#include <hip/hip_runtime.h>

#define NODES 50000
#define CH 128
#define ELLW 64

using frag_ab = __attribute__((ext_vector_type(8))) short;   // 8 bf16
using frag_cd = __attribute__((ext_vector_type(4))) float;   // 4 fp32

__device__ __forceinline__ float bf2f(ushort u) {
    union { unsigned u; float f; } v; v.u = ((unsigned)u) << 16; return v.f;
}
__device__ __forceinline__ ushort f2bf(float f) {
    union { float f; unsigned u; } v; v.f = f;
    unsigned r = v.u + 0x7fff + ((v.u >> 16) & 1);   // RNE
    return (ushort)(r >> 16);
}

// ---------------- prep: 5 weight transposes + deg zeroing, ONE dispatch ----------------
__global__ void prep_weights(const float* __restrict__ Wlin,
                             const float* __restrict__ W1l, const float* __restrict__ W1r,
                             const float* __restrict__ W2l, const float* __restrict__ W2r,
                             ushort* __restrict__ o0, ushort* __restrict__ o1,
                             ushort* __restrict__ o2, ushort* __restrict__ o3,
                             ushort* __restrict__ o4, int* __restrict__ deg) {
    int b = blockIdx.x;
    if (b >= 448) {
        int i = (b - 448) * 256 + threadIdx.y * 128 + threadIdx.x;
        if (i < NODES) deg[i] = 0;
        return;
    }
    const float* W; ushort* O; int K; int kb;
    if (b < 192) { W = Wlin; O = o0; K = 384; kb = b; }
    else {
        int j = (b - 192) >> 6; kb = (b - 192) & 63; K = 128;
        W = (j == 0) ? W1l : (j == 1) ? W1r : (j == 2) ? W2l : W2r;
        O = (j == 0) ? o1  : (j == 1) ? o2  : (j == 2) ? o3  : o4;
    }
    int k = kb * 2 + threadIdx.y;
    int n = threadIdx.x;
    if (k < K) O[(size_t)n * K + k] = f2bf(W[(size_t)k * 128 + n]);
}

// ---------------- ELL build ----------------
__global__ void fill_ell(const int* __restrict__ ei, int E,
                         int* __restrict__ deg, int* __restrict__ ell) {
    int e = blockIdx.x * blockDim.x + threadIdx.x;
    if (e < E) {
        int d = ei[E + e];
        int pos = atomicAdd(&deg[d], 1);
        if (pos < ELLW) ell[(size_t)d * ELLW + pos] = ei[e];
    }
}

// ---------------- mean aggregation over ELL ----------------
// wave = one node; g=lane>>4 picks neighbor-in-group-of-4, q=lane&15 picks 16B chunk.
// 1KB/load-instruction, 8 rows in flight; shfl_xor(16,32) cross-group reduce.
__global__ __launch_bounds__(256) void aggregate_ell(
    const ushort* __restrict__ h, const int* __restrict__ ell,
    const int* __restrict__ deg, ushort* __restrict__ mean, int N) {
    int node = blockIdx.x * 4 + (threadIdx.x >> 6);
    if (node >= N) return;
    int lane = threadIdx.x & 63;
    int g = lane >> 4;
    int q = lane & 15;
    const int* row = ell + (size_t)node * ELLW;
    int d = deg[node];
    int dc = d < ELLW ? d : ELLW;

    float acc[8];
#pragma unroll
    for (int k = 0; k < 8; ++k) acc[k] = 0.f;

    int n = 0;
    for (; n + 8 <= dc; n += 8) {
        int i0 = row[n + g];
        int i1 = row[n + 4 + g];
        uint4 v0 = *(const uint4*)(h + (size_t)i0 * CH + q * 8);
        uint4 v1 = *(const uint4*)(h + (size_t)i1 * CH + q * 8);
        acc[0] += bf2f((ushort)(v0.x & 0xffff)); acc[1] += bf2f((ushort)(v0.x >> 16));
        acc[2] += bf2f((ushort)(v0.y & 0xffff)); acc[3] += bf2f((ushort)(v0.y >> 16));
        acc[4] += bf2f((ushort)(v0.z & 0xffff)); acc[5] += bf2f((ushort)(v0.z >> 16));
        acc[6] += bf2f((ushort)(v0.w & 0xffff)); acc[7] += bf2f((ushort)(v0.w >> 16));
        acc[0] += bf2f((ushort)(v1.x & 0xffff)); acc[1] += bf2f((ushort)(v1.x >> 16));
        acc[2] += bf2f((ushort)(v1.y & 0xffff)); acc[3] += bf2f((ushort)(v1.y >> 16));
        acc[4] += bf2f((ushort)(v1.z & 0xffff)); acc[5] += bf2f((ushort)(v1.z >> 16));
        acc[6] += bf2f((ushort)(v1.w & 0xffff)); acc[7] += bf2f((ushort)(v1.w >> 16));
    }
    for (; n < dc; n += 4) {
        int j = n + g;
        if (j < dc) {
            int i0 = row[j];
            uint4 v0 = *(const uint4*)(h + (size_t)i0 * CH + q * 8);
            acc[0] += bf2f((ushort)(v0.x & 0xffff)); acc[1] += bf2f((ushort)(v0.x >> 16));
            acc[2] += bf2f((ushort)(v0.y & 0xffff)); acc[3] += bf2f((ushort)(v0.y >> 16));
            acc[4] += bf2f((ushort)(v0.z & 0xffff)); acc[5] += bf2f((ushort)(v0.z >> 16));
            acc[6] += bf2f((ushort)(v0.w & 0xffff)); acc[7] += bf2f((ushort)(v0.w >> 16));
        }
    }
#pragma unroll
    for (int k = 0; k < 8; ++k) {
        acc[k] += __shfl_xor(acc[k], 16, 64);
        acc[k] += __shfl_xor(acc[k], 32, 64);
    }
    if (g == 0) {
        float inv = 1.f / fmaxf((float)d, 1.f);
        uint4 o;
        o.x = ((uint)f2bf(acc[1] * inv) << 16) | (uint)f2bf(acc[0] * inv);
        o.y = ((uint)f2bf(acc[3] * inv) << 16) | (uint)f2bf(acc[2] * inv);
        o.z = ((uint)f2bf(acc[5] * inv) << 16) | (uint)f2bf(acc[4] * inv);
        o.w = ((uint)f2bf(acc[7] * inv) << 16) | (uint)f2bf(acc[6] * inv);
        *(uint4*)(mean + (size_t)node * CH + q * 8) = o;
    }
}

// ---------------- gemm_lin: out = f2bf(x) @ WtLin^T + bias ----------------
__global__ __launch_bounds__(256) void gemm_lin(
    const float* __restrict__ A, const ushort* __restrict__ Wt,
    const float* __restrict__ bias, ushort* __restrict__ out, int N)
{
    __shared__ ushort As[128 * 32];
    __shared__ ushort Bs[128 * 32];
    const int tid = threadIdx.x;
    const int lane = tid & 63;
    const int wave = tid >> 6;
    const int wr = wave >> 1, wc = wave & 1;
    const int row0 = blockIdx.x * 128;
    const int l15 = lane & 15, quad = lane >> 4;

    frag_cd acc[4][4];
#pragma unroll
    for (int i = 0; i < 4; ++i)
#pragma unroll
        for (int j = 0; j < 4; ++j) acc[i][j] = (frag_cd){0.f, 0.f, 0.f, 0.f};

#pragma unroll 1
    for (int k0 = 0; k0 < 384; k0 += 32) {
        __syncthreads();
#pragma unroll
        for (int i = 0; i < 4; ++i) {
            int e = i * 256 + tid;
            int r = e >> 3, q = e & 7;
            int gr = row0 + r; if (gr > N - 1) gr = N - 1;
            float4 v = *(const float4*)(A + (size_t)gr * 384 + k0 + q * 4);
            ushort4 o; o.x = f2bf(v.x); o.y = f2bf(v.y); o.z = f2bf(v.z); o.w = f2bf(v.w);
            *(ushort4*)(As + r * 32 + q * 4) = o;
        }
#pragma unroll
        for (int i = 0; i < 2; ++i) {
            int e = i * 256 + tid;
            int nn = e >> 2, kq = e & 3;
            uint4 v = *(const uint4*)(Wt + (size_t)nn * 384 + k0 + kq * 8);
            *(uint4*)(Bs + e * 8) = v;
        }
        __syncthreads();

        frag_ab a[4], b[4];
#pragma unroll
        for (int i = 0; i < 4; ++i)
            a[i] = *(const frag_ab*)(As + (wr * 64 + i * 16 + l15) * 32 + quad * 8);
#pragma unroll
        for (int j = 0; j < 4; ++j)
            b[j] = *(const frag_ab*)(Bs + (wc * 64 + j * 16 + l15) * 32 + quad * 8);
#pragma unroll
        for (int i = 0; i < 4; ++i)
#pragma unroll
            for (int j = 0; j < 4; ++j)
                acc[i][j] = __builtin_amdgcn_mfma_f32_16x16x32_bf16(a[i], b[j], acc[i][j], 0, 0, 0);
    }

#pragma unroll
    for (int i = 0; i < 4; ++i)
#pragma unroll
        for (int r = 0; r < 4; ++r) {
            int row = row0 + wr * 64 + i * 16 + quad * 4 + r;
            if (row < N)
#pragma unroll
                for (int j = 0; j < 4; ++j) {
                    int col = wc * 64 + j * 16 + l15;
                    out[(size_t)row * 128 + col] = f2bf(acc[i][j][r] + bias[col]);
                }
        }
}

// ---------------- dual-input MFMA GEMM (K=128 each) ----------------
template <bool RELU>
__global__ __launch_bounds__(256) void mfma_gemm(
    const ushort* __restrict__ A1, const ushort* __restrict__ Wt1,
    const ushort* __restrict__ A2, const ushort* __restrict__ Wt2,
    const float* __restrict__ bias, ushort* __restrict__ out, int N)
{
    __shared__ ushort As[128 * 32];
    __shared__ ushort Bs[128 * 32];
    const int tid = threadIdx.x;
    const int lane = tid & 63;
    const int wave = tid >> 6;
    const int wr = wave >> 1, wc = wave & 1;
    const int row0 = blockIdx.x * 128;
    const int l15 = lane & 15, quad = lane >> 4;

    frag_cd acc[4][4];
#pragma unroll
    for (int i = 0; i < 4; ++i)
#pragma unroll
        for (int j = 0; j < 4; ++j) acc[i][j] = (frag_cd){0.f, 0.f, 0.f, 0.f};

#pragma unroll 1
    for (int part = 0; part < 2; ++part) {
        const ushort* A  = part ? A2 : A1;
        const ushort* Wt = part ? Wt2 : Wt1;

#pragma unroll 1
        for (int k0 = 0; k0 < 128; k0 += 32) {
            __syncthreads();
#pragma unroll
            for (int i = 0; i < 2; ++i) {
                int e = i * 256 + tid;
                int r = e >> 2, kq = e & 3;
                int gr = row0 + r; if (gr > N - 1) gr = N - 1;
                uint4 v = *(const uint4*)(A + (size_t)gr * 128 + k0 + kq * 8);
                *(uint4*)(As + e * 8) = v;
            }
#pragma unroll
            for (int i = 0; i < 2; ++i) {
                int e = i * 256 + tid;
                int nn = e >> 2, kq = e & 3;
                uint4 v = *(const uint4*)(Wt + (size_t)nn * 128 + k0 + kq * 8);
                *(uint4*)(Bs + e * 8) = v;
            }
            __syncthreads();

            frag_ab a[4], b[4];
#pragma unroll
            for (int i = 0; i < 4; ++i)
                a[i] = *(const frag_ab*)(As + (wr * 64 + i * 16 + l15) * 32 + quad * 8);
#pragma unroll
            for (int j = 0; j < 4; ++j)
                b[j] = *(const frag_ab*)(Bs + (wc * 64 + j * 16 + l15) * 32 + quad * 8);
#pragma unroll
            for (int i = 0; i < 4; ++i)
#pragma unroll
                for (int j = 0; j < 4; ++j)
                    acc[i][j] = __builtin_amdgcn_mfma_f32_16x16x32_bf16(a[i], b[j], acc[i][j], 0, 0, 0);
        }
    }

#pragma unroll
    for (int i = 0; i < 4; ++i)
#pragma unroll
        for (int r = 0; r < 4; ++r) {
            int row = row0 + wr * 64 + i * 16 + quad * 4 + r;
            if (row < N)
#pragma unroll
                for (int j = 0; j < 4; ++j) {
                    int col = wc * 64 + j * 16 + l15;
                    float v = acc[i][j][r] + bias[col];
                    if (RELU) v = fmaxf(v, 0.f);
                    out[(size_t)row * 128 + col] = f2bf(v);
                }
        }
}

// ---------------- classifier: 4 edges / 16-lane group ----------------
__device__ __forceinline__ float dot8(uint4 va, uint4 vb) {
    float p = 0.f;
    p += bf2f((ushort)(va.x & 0xffff)) * bf2f((ushort)(vb.x & 0xffff));
    p += bf2f((ushort)(va.x >> 16))    * bf2f((ushort)(vb.x >> 16));
    p += bf2f((ushort)(va.y & 0xffff)) * bf2f((ushort)(vb.y & 0xffff));
    p += bf2f((ushort)(va.y >> 16))    * bf2f((ushort)(vb.y >> 16));
    p += bf2f((ushort)(va.z & 0xffff)) * bf2f((ushort)(vb.z & 0xffff));
    p += bf2f((ushort)(va.z >> 16))    * bf2f((ushort)(vb.z >> 16));
    p += bf2f((ushort)(va.w & 0xffff)) * bf2f((ushort)(vb.w & 0xffff));
    p += bf2f((ushort)(va.w >> 16))    * bf2f((ushort)(vb.w >> 16));
    return p;
}

__global__ __launch_bounds__(256) void classify_bf(
    const ushort* __restrict__ h2, const int* __restrict__ eli,
    int EL, float* __restrict__ out) {
    int gt = blockIdx.x * blockDim.x + threadIdx.x;
    int g0 = (gt >> 4) * 4;
    int lane = gt & 15;
    if (g0 >= EL) return;
    bool full = (g0 + 3 < EL);
    int4 ha, ta;
    if (full) {
        ha = *(const int4*)(eli + g0);
        ta = *(const int4*)(eli + EL + g0);
    } else {
        int e1 = g0 + 1 < EL ? g0 + 1 : g0;
        int e2 = g0 + 2 < EL ? g0 + 2 : g0;
        ha = make_int4(eli[g0], eli[e1], eli[e2], eli[e2]);
        ta = make_int4(eli[EL + g0], eli[EL + e1], eli[EL + e2], eli[EL + e2]);
    }
    uint4 va0 = *((const uint4*)(h2 + (size_t)ha.x * CH) + lane);
    uint4 vb0 = *((const uint4*)(h2 + (size_t)ta.x * CH) + lane);
    uint4 va1 = *((const uint4*)(h2 + (size_t)ha.y * CH) + lane);
    uint4 vb1 = *((const uint4*)(h2 + (size_t)ta.y * CH) + lane);
    uint4 va2 = *((const uint4*)(h2 + (size_t)ha.z * CH) + lane);
    uint4 vb2 = *((const uint4*)(h2 + (size_t)ta.z * CH) + lane);
    uint4 va3 = *((const uint4*)(h2 + (size_t)ha.w * CH) + lane);
    uint4 vb3 = *((const uint4*)(h2 + (size_t)ta.w * CH) + lane);
    float p0 = dot8(va0, vb0);
    float p1 = dot8(va1, vb1);
    float p2 = dot8(va2, vb2);
    float p3 = dot8(va3, vb3);
#pragma unroll
    for (int s = 8; s >= 1; s >>= 1) {
        p0 += __shfl_down(p0, s, 16);
        p1 += __shfl_down(p1, s, 16);
        p2 += __shfl_down(p2, s, 16);
        p3 += __shfl_down(p3, s, 16);
    }
    if (lane == 0) {
        if (full) {
            *(float4*)(out + g0) = make_float4(p0, p1, p2, p3);
        } else {
            out[g0] = p0;
            if (g0 + 1 < EL) out[g0 + 1] = p1;
            if (g0 + 2 < EL) out[g0 + 2] = p2;
        }
    }
}

extern "C" void kernel_launch(void* const* d_in, const int* in_sizes, int n_in,
                              void* d_out, int out_size, void* d_ws, size_t ws_size,
                              hipStream_t stream) {
    const float* x     = (const float*)d_in[0];
    const int*   ei    = (const int*)d_in[1];
    const int*   eli   = (const int*)d_in[2];
    const float* W_lin = (const float*)d_in[3];
    const float* b_lin = (const float*)d_in[4];
    const float* W1l   = (const float*)d_in[5];
    const float* b1    = (const float*)d_in[6];
    const float* W1r   = (const float*)d_in[7];
    const float* W2l   = (const float*)d_in[8];
    const float* b2    = (const float*)d_in[9];
    const float* W2r   = (const float*)d_in[10];
    float* out = (float*)d_out;

    const int E  = in_sizes[1] / 2;
    const int EL = in_sizes[2] / 2;
    const int N  = NODES;

    char* ws = (char*)d_ws;
    size_t off = 0;
    auto alloc = [&](size_t bytes) -> void* {
        void* p = ws + off;
        off += (bytes + 255) & ~(size_t)255;
        return p;
    };
    ushort* n0    = (ushort*)alloc((size_t)N * CH * sizeof(ushort));  // h0, then h2
    ushort* n1    = (ushort*)alloc((size_t)N * CH * sizeof(ushort));  // mean1 / mean2
    ushort* n2    = (ushort*)alloc((size_t)N * CH * sizeof(ushort));  // h1
    ushort* WtLin = (ushort*)alloc((size_t)CH * 384 * sizeof(ushort));
    ushort* Wt1l  = (ushort*)alloc((size_t)CH * CH * sizeof(ushort));
    ushort* Wt1r  = (ushort*)alloc((size_t)CH * CH * sizeof(ushort));
    ushort* Wt2l  = (ushort*)alloc((size_t)CH * CH * sizeof(ushort));
    ushort* Wt2r  = (ushort*)alloc((size_t)CH * CH * sizeof(ushort));
    int* deg = (int*)alloc((size_t)N * sizeof(int));
    int* ell = (int*)alloc((size_t)N * ELLW * sizeof(int));
    (void)ws_size; (void)n_in; (void)out_size;

    prep_weights<<<dim3(644), dim3(128, 2), 0, stream>>>(
        W_lin, W1l, W1r, W2l, W2r, WtLin, Wt1l, Wt1r, Wt2l, Wt2r, deg);

    fill_ell<<<dim3((E + 255) / 256), dim3(256), 0, stream>>>(ei, E, deg, ell);

    const int gblocks = (N + 127) / 128;
    const int ablocks = (N + 3) / 4;

    // h0 = bf16(x) @ W_lin + b_lin   -> n0
    gemm_lin<<<dim3(gblocks), dim3(256), 0, stream>>>(x, WtLin, b_lin, n0, N);

    // layer 1: mean1 -> n1; h1 = relu(mean1@W1l + h0@W1r + b1) -> n2
    aggregate_ell<<<dim3(ablocks), dim3(256), 0, stream>>>(n0, ell, deg, n1, N);
    mfma_gemm<true><<<dim3(gblocks), dim3(256), 0, stream>>>(
        n1, Wt1l, n0, Wt1r, b1, n2, N);

    // layer 2: mean2 -> n1; h2 = mean2@W2l + h1@W2r + b2 -> n0
    aggregate_ell<<<dim3(ablocks), dim3(256), 0, stream>>>(n2, ell, deg, n1, N);
    mfma_gemm<false><<<dim3(gblocks), dim3(256), 0, stream>>>(
        n1, Wt2l, n2, Wt2r, b2, n0, N);

    // classifier on h2 = n0
    long long groups = ((long long)EL + 3) / 4;
    long long cls_threads = groups * 16;
    classify_bf<<<dim3((int)((cls_threads + 255) / 256)), dim3(256), 0, stream>>>(
        n0, eli, EL, out);
}